// Round 4
// baseline (4082.776 us; speedup 1.0000x reference)
//
#include <hip/hip_runtime.h>
#include <hip/hip_fp16.h>
#include <math.h>

// Problem geometry (fixed by the reference)
#define BATCH   32
#define NHEAD   32
#define DIM     64
#define SEQ     4096
#define START   4080
#define NSTEPS  16
#define SCALE   0.125f
#define NTHR    512          // threads per block (8 waves)
#define DYN_LDS 57344        // dynamic-LDS pad: forces 1 block/CU (residency)

typedef float fvec4 __attribute__((ext_vector_type(4)));  // nontemporal-loadable

// One block per (b,h) chain: 1024 blocks x 512 threads, 16 sequential decode
// steps. fp16 shadow copy of K/V written during step 0, read steps 1..15.
// LDS padded past 80 KiB so only ~256 blocks (1/CU) are resident: the live
// fp16 working set (256 x 1.0 MB) then fits the 256 MB Infinity Cache, and
// steps 1..15 stream from L3 instead of HBM. Step-0 f32 reads use
// nontemporal loads so the one-shot stream doesn't evict the fp16 shadow.
template <bool USE_WS>
__launch_bounds__(NTHR, 1)
__global__ void attn_unroll_kernel(const float* __restrict__ x_in,
                                   const float* __restrict__ k_in,
                                   const float* __restrict__ v_in,
                                   const float* __restrict__ wq,
                                   const float* __restrict__ wk,
                                   const float* __restrict__ wv,
                                   const float* __restrict__ wo,
                                   float* __restrict__ out,
                                   __half* __restrict__ kh_ws,
                                   __half* __restrict__ vh_ws)
{
    extern __shared__ float s_pad[];     // residency throttle (never touched)
    (void)s_pad;

    const int bid = blockIdx.x;          // b*NHEAD + h
    const int h   = bid & (NHEAD - 1);
    const int tid = threadIdx.x;         // 0..511

    __shared__ float s_scores[SEQ];          // 16 KiB
    __shared__ float s_kext[NSTEPS][DIM];    // 4 KiB
    __shared__ float s_vext[NSTEPS][DIM];    // 4 KiB
    __shared__ float s_x[DIM];
    __shared__ float s_q[DIM];
    __shared__ float s_attn[DIM];
    __shared__ float s_red[8][DIM];          // cross-wave reduce, 2 KiB
    __shared__ float s_wred[8];

    const float* __restrict__ K  = k_in + (size_t)bid * SEQ * DIM;
    const float* __restrict__ V  = v_in + (size_t)bid * SEQ * DIM;
    const float* __restrict__ Wq = wq + (size_t)h * DIM * DIM;
    const float* __restrict__ Wk = wk + (size_t)h * DIM * DIM;
    const float* __restrict__ Wv = wv + (size_t)h * DIM * DIM;
    const float* __restrict__ Wo = wo + (size_t)h * DIM * DIM;
    __half* __restrict__ Kh = USE_WS ? kh_ws + (size_t)bid * START * DIM : nullptr;
    __half* __restrict__ Vh = USE_WS ? vh_ws + (size_t)bid * START * DIM : nullptr;

    // ---- init: x vector + ext rows (original cache tail) ----
    if (tid < DIM) s_x[tid] = x_in[(size_t)bid * DIM + tid];
    for (int i = tid; i < NSTEPS * DIM; i += NTHR) {
        (&s_kext[0][0])[i] = K[(size_t)START * DIM + i];
        (&s_vext[0][0])[i] = V[(size_t)START * DIM + i];
    }
    __syncthreads();

    // out_vec[e] = sum_d in_vec[d] * W[d*64+e]   (einsum "d,de->e")
    auto project = [&](const float* in_vec, const float* __restrict__ W,
                       float* out_vec) {
        const int e = tid & 63;
        const int g = tid >> 6;              // 8 groups of 8 d-values
        float p = 0.f;
        #pragma unroll
        for (int dd = 0; dd < 8; ++dd) {
            const int d0 = g * 8 + dd;
            p += in_vec[d0] * W[d0 * 64 + e];   // coalesced over e
        }
        s_red[g][e] = p;
        __syncthreads();
        if (tid < 64) {
            float r = 0.f;
            #pragma unroll
            for (int w = 0; w < 8; ++w) r += s_red[w][tid];
            out_vec[tid] = r;
        }
        __syncthreads();
    };

    const int c    = tid & 15;   // f32 path: 16B chunk (4 floats) within a row
    const int sr   = tid >> 4;   //           row within a 32-row tile [0,32)
    const int c8   = tid & 7;    // f16 path: 16B chunk (8 halves) within a row
    const int rg   = tid >> 3;   //           row within a 64-row tile [0,64)
    const int wave = tid >> 6;   // [0,8)

    // ---- QK pass, f32 cache (step 0); also emits the fp16 shadow copy ----
    auto qk_f32 = [&]() {
        const float q0 = s_q[c * 4 + 0], q1 = s_q[c * 4 + 1];
        const float q2 = s_q[c * 4 + 2], q3 = s_q[c * 4 + 3];
        const fvec4* __restrict__ K4 = (const fvec4*)K;
        auto row = [&](int s, fvec4 kv) {
            if (USE_WS) {
                __half2* dst = (__half2*)(Kh + (size_t)s * DIM + c * 4);
                dst[0] = __floats2half2_rn(kv.x, kv.y);
                dst[1] = __floats2half2_rn(kv.z, kv.w);
            }
            float p = kv.x * q0 + kv.y * q1 + kv.z * q2 + kv.w * q3;
            p += __shfl_xor(p, 1);
            p += __shfl_xor(p, 2);
            p += __shfl_xor(p, 4);
            p += __shfl_xor(p, 8);
            if (c == 0) s_scores[s] = p;
        };
        for (int it = 0; it < 127; ++it) {               // rows 0..4063
            const int s = it * 32 + sr;
            row(s, __builtin_nontemporal_load(&K4[s * 16 + c]));
        }
        if (sr < 16) {                                    // tail rows 4064..4079
            const int s = 4064 + sr;
            row(s, __builtin_nontemporal_load(&K4[s * 16 + c]));
        }
        if (sr < 16) {                                    // ext rows from LDS
            const int s = START + sr;
            const float* kr = s_kext[sr];
            float p = kr[c * 4 + 0] * q0 + kr[c * 4 + 1] * q1
                    + kr[c * 4 + 2] * q2 + kr[c * 4 + 3] * q3;
            p += __shfl_xor(p, 1);
            p += __shfl_xor(p, 2);
            p += __shfl_xor(p, 4);
            p += __shfl_xor(p, 8);
            if (c == 0) s_scores[s] = p;
        }
    };

    // ---- QK pass, fp16 shadow cache (steps 1..15) ----
    auto qk_h = [&]() {
        float qv[8];
        #pragma unroll
        for (int j = 0; j < 8; ++j) qv[j] = s_q[c8 * 8 + j];
        const fvec4* __restrict__ Kh4 = (const fvec4*)Kh;
        auto row = [&](int s) {
            fvec4 raw = Kh4[(size_t)s * 8 + c8];
            const __half2* hp = (const __half2*)&raw;
            float p = 0.f;
            #pragma unroll
            for (int j = 0; j < 4; ++j) {
                const float2 f = __half22float2(hp[j]);
                p += f.x * qv[2 * j] + f.y * qv[2 * j + 1];
            }
            p += __shfl_xor(p, 1);
            p += __shfl_xor(p, 2);
            p += __shfl_xor(p, 4);
            if (c8 == 0) s_scores[s] = p;
        };
        for (int it = 0; it < 63; ++it)                   // rows 0..4031
            row(it * 64 + rg);
        if (rg < 48)                                      // tail 4032..4079
            row(4032 + rg);
        if (rg < 16) {                                    // ext rows from LDS
            const float* kr = s_kext[rg];
            float p = 0.f;
            #pragma unroll
            for (int j = 0; j < 8; ++j) p += kr[c8 * 8 + j] * qv[j];
            p += __shfl_xor(p, 1);
            p += __shfl_xor(p, 2);
            p += __shfl_xor(p, 4);
            if (c8 == 0) s_scores[START + rg] = p;
        }
    };

    // ---- PV pass, f32 cache (step 0); also emits the fp16 shadow copy ----
    auto pv_f32 = [&](float inv_total) {
        float ax = 0.f, ay = 0.f, az = 0.f, aw = 0.f;
        const fvec4* __restrict__ V4 = (const fvec4*)V;
        auto row = [&](int s, fvec4 vv) {
            if (USE_WS) {
                __half2* dst = (__half2*)(Vh + (size_t)s * DIM + c * 4);
                dst[0] = __floats2half2_rn(vv.x, vv.y);
                dst[1] = __floats2half2_rn(vv.z, vv.w);
            }
            const float a = s_scores[s];
            ax += a * vv.x; ay += a * vv.y; az += a * vv.z; aw += a * vv.w;
        };
        for (int it = 0; it < 127; ++it) {
            const int s = it * 32 + sr;
            row(s, __builtin_nontemporal_load(&V4[s * 16 + c]));
        }
        if (sr < 16) {
            const int s = 4064 + sr;
            row(s, __builtin_nontemporal_load(&V4[s * 16 + c]));
        }
        if (sr < 16) {
            const int s = START + sr;
            const float a  = s_scores[s];
            const float* vr = s_vext[sr];
            ax += a * vr[c * 4 + 0]; ay += a * vr[c * 4 + 1];
            az += a * vr[c * 4 + 2]; aw += a * vr[c * 4 + 3];
        }
        ax += __shfl_xor(ax, 16); ax += __shfl_xor(ax, 32);
        ay += __shfl_xor(ay, 16); ay += __shfl_xor(ay, 32);
        az += __shfl_xor(az, 16); az += __shfl_xor(az, 32);
        aw += __shfl_xor(aw, 16); aw += __shfl_xor(aw, 32);
        if ((tid & 63) < 16) {
            s_red[wave][c * 4 + 0] = ax;
            s_red[wave][c * 4 + 1] = ay;
            s_red[wave][c * 4 + 2] = az;
            s_red[wave][c * 4 + 3] = aw;
        }
        __syncthreads();
        if (tid < 64) {
            float r = 0.f;
            #pragma unroll
            for (int w = 0; w < 8; ++w) r += s_red[w][tid];
            s_attn[tid] = r * inv_total;
        }
        __syncthreads();
    };

    // ---- PV pass, fp16 shadow cache (steps 1..15) ----
    auto pv_h = [&](float inv_total) {
        float a[8];
        #pragma unroll
        for (int j = 0; j < 8; ++j) a[j] = 0.f;
        const fvec4* __restrict__ Vh4 = (const fvec4*)Vh;
        auto row = [&](int s) {
            const float w = s_scores[s];
            fvec4 raw = Vh4[(size_t)s * 8 + c8];
            const __half2* hp = (const __half2*)&raw;
            #pragma unroll
            for (int j = 0; j < 4; ++j) {
                const float2 f = __half22float2(hp[j]);
                a[2 * j + 0] += w * f.x;
                a[2 * j + 1] += w * f.y;
            }
        };
        for (int it = 0; it < 63; ++it)
            row(it * 64 + rg);
        if (rg < 48)
            row(4032 + rg);
        if (rg < 16) {
            const float w = s_scores[START + rg];
            const float* vr = s_vext[rg];
            #pragma unroll
            for (int j = 0; j < 8; ++j) a[j] += w * vr[c8 * 8 + j];
        }
        #pragma unroll
        for (int j = 0; j < 8; ++j) {
            a[j] += __shfl_xor(a[j], 8);
            a[j] += __shfl_xor(a[j], 16);
            a[j] += __shfl_xor(a[j], 32);
        }
        if ((tid & 63) < 8) {
            #pragma unroll
            for (int j = 0; j < 8; ++j) s_red[wave][c8 * 8 + j] = a[j];
        }
        __syncthreads();
        if (tid < 64) {
            float r = 0.f;
            #pragma unroll
            for (int w = 0; w < 8; ++w) r += s_red[w][tid];
            s_attn[tid] = r * inv_total;
        }
        __syncthreads();
    };

    for (int step = 0; step < NSTEPS; ++step) {
        // ---- projections (q scaled; k_new/v_new overwrite ext row `step`) ----
        project(s_x, Wq, s_q);
        project(s_x, Wk, s_kext[step]);
        project(s_x, Wv, s_vext[step]);
        if (tid < 64) s_q[tid] *= SCALE;
        __syncthreads();

        if (USE_WS && step > 0) qk_h(); else qk_f32();
        __syncthreads();

        // ---- softmax over 4096 scores (normalization folded into PV) ----
        float lmax = -1e30f;
        #pragma unroll
        for (int i = 0; i < 8; ++i)
            lmax = fmaxf(lmax, s_scores[tid + i * NTHR]);
        #pragma unroll
        for (int off = 1; off < 64; off <<= 1)
            lmax = fmaxf(lmax, __shfl_xor(lmax, off));
        if ((tid & 63) == 0) s_wred[wave] = lmax;
        __syncthreads();
        float bmax = s_wred[0];
        #pragma unroll
        for (int w = 1; w < 8; ++w) bmax = fmaxf(bmax, s_wred[w]);
        float lsum = 0.f;
        #pragma unroll
        for (int i = 0; i < 8; ++i) {
            const float e = __expf(s_scores[tid + i * NTHR] - bmax);
            s_scores[tid + i * NTHR] = e;
            lsum += e;
        }
        #pragma unroll
        for (int off = 1; off < 64; off <<= 1)
            lsum += __shfl_xor(lsum, off);
        __syncthreads();                       // s_wred reuse + exp writes
        if ((tid & 63) == 0) s_wred[wave] = lsum;
        __syncthreads();
        float tot = 0.f;
        #pragma unroll
        for (int w = 0; w < 8; ++w) tot += s_wred[w];
        const float inv_total = 1.f / tot;

        if (USE_WS && step > 0) pv_h(inv_total); else pv_f32(inv_total);

        // ---- output projection -> new x ----
        project(s_attn, Wo, s_x);
    }

    if (tid < 64) out[(size_t)bid * DIM + tid] = s_x[tid];
}

extern "C" void kernel_launch(void* const* d_in, const int* in_sizes, int n_in,
                              void* d_out, int out_size, void* d_ws, size_t ws_size,
                              hipStream_t stream) {
    const float* x  = (const float*)d_in[0];
    const float* k  = (const float*)d_in[1];
    const float* v  = (const float*)d_in[2];
    const float* wq = (const float*)d_in[3];
    const float* wk = (const float*)d_in[4];
    const float* wv = (const float*)d_in[5];
    const float* wo = (const float*)d_in[6];
    float* out = (float*)d_out;

    const size_t half_elems = (size_t)BATCH * NHEAD * START * DIM;  // per array
    const size_t need = 2 * half_elems * sizeof(__half);            // K + V

    if (ws_size >= need) {
        __half* kh = (__half*)d_ws;
        __half* vh = kh + half_elems;
        attn_unroll_kernel<true><<<BATCH * NHEAD, NTHR, DYN_LDS, stream>>>(
            x, k, v, wq, wk, wv, wo, out, kh, vh);
    } else {
        attn_unroll_kernel<false><<<BATCH * NHEAD, NTHR, DYN_LDS, stream>>>(
            x, k, v, wq, wk, wv, wo, out, nullptr, nullptr);
    }
}

// Round 5
// 3745.552 us; speedup vs baseline: 1.0900x; 1.0900x over previous
//
#include <hip/hip_runtime.h>
#include <hip/hip_fp16.h>
#include <math.h>

// Problem geometry (fixed by the reference)
#define BATCH   32
#define NHEAD   32
#define DIM     64
#define SEQ     4096
#define START   4080
#define NSTEPS  16
#define SCALE   0.125f

typedef float fvec4 __attribute__((ext_vector_type(4)));  // nontemporal-loadable

// One block per (b,h) chain: 1024 blocks x 256 threads, 16 sequential decode
// steps. fp16 shadow of K/V written during step 0 (nontemporal f32 reads),
// read in steps 1..15 (half the bytes). launch_bounds(256,6): 6 blocks/CU
// (LDS 6x26.6KB = 159.7KB fits the 160KB pool) -> 24 waves/CU for latency
// hiding; round-4 showed the limiter is per-CU load delivery, not HBM.
template <bool USE_WS>
__launch_bounds__(256, 6)
__global__ void attn_unroll_kernel(const float* __restrict__ x_in,
                                   const float* __restrict__ k_in,
                                   const float* __restrict__ v_in,
                                   const float* __restrict__ wq,
                                   const float* __restrict__ wk,
                                   const float* __restrict__ wv,
                                   const float* __restrict__ wo,
                                   float* __restrict__ out,
                                   __half* __restrict__ kh_ws,
                                   __half* __restrict__ vh_ws)
{
    const int bid = blockIdx.x;          // b*NHEAD + h
    const int h   = bid & (NHEAD - 1);
    const int tid = threadIdx.x;         // 0..255

    __shared__ float s_scores[SEQ];          // 16 KiB
    __shared__ float s_kext[NSTEPS][DIM];    // 4 KiB
    __shared__ float s_vext[NSTEPS][DIM];    // 4 KiB
    __shared__ float s_x[DIM];
    __shared__ float s_q[DIM];
    __shared__ float s_attn[DIM];
    __shared__ float s_red[4][DIM];          // cross-wave reduce, 1 KiB
    __shared__ float s_wred[4];

    const float* __restrict__ K  = k_in + (size_t)bid * SEQ * DIM;
    const float* __restrict__ V  = v_in + (size_t)bid * SEQ * DIM;
    const float* __restrict__ Wq = wq + (size_t)h * DIM * DIM;
    const float* __restrict__ Wk = wk + (size_t)h * DIM * DIM;
    const float* __restrict__ Wv = wv + (size_t)h * DIM * DIM;
    const float* __restrict__ Wo = wo + (size_t)h * DIM * DIM;
    __half* __restrict__ Kh = USE_WS ? kh_ws + (size_t)bid * START * DIM : nullptr;
    __half* __restrict__ Vh = USE_WS ? vh_ws + (size_t)bid * START * DIM : nullptr;

    // ---- init: x vector + ext rows (original cache tail) ----
    if (tid < DIM) s_x[tid] = x_in[(size_t)bid * DIM + tid];
    for (int i = tid; i < NSTEPS * DIM; i += 256) {
        (&s_kext[0][0])[i] = K[(size_t)START * DIM + i];
        (&s_vext[0][0])[i] = V[(size_t)START * DIM + i];
    }
    __syncthreads();

    // out_vec[e] = sum_d in_vec[d] * W[d*64+e]   (einsum "d,de->e")
    auto project = [&](const float* in_vec, const float* __restrict__ W,
                       float* out_vec) {
        const int e = tid & 63;
        const int g = tid >> 6;              // 4 groups of 16 d-values
        float p = 0.f;
        #pragma unroll
        for (int dd = 0; dd < 16; ++dd) {
            const int d0 = g * 16 + dd;
            p += in_vec[d0] * W[d0 * 64 + e];   // coalesced over e
        }
        s_red[g][e] = p;
        __syncthreads();
        if (tid < 64)
            out_vec[tid] = s_red[0][tid] + s_red[1][tid]
                         + s_red[2][tid] + s_red[3][tid];
        __syncthreads();
    };

    const int c    = tid & 15;   // f32 path: 16B chunk (4 floats) within a row
    const int sr   = tid >> 4;   //           row within a 16-row tile [0,16)
    const int c8   = tid & 7;    // f16 path: 16B chunk (8 halves) within a row
    const int rg   = tid >> 3;   //           row within a 32-row tile [0,32)
    const int wave = tid >> 6;   // [0,4)

    // ---- QK pass, f32 cache (step 0); also emits the fp16 shadow copy ----
    auto qk_f32 = [&]() {
        const float q0 = s_q[c * 4 + 0], q1 = s_q[c * 4 + 1];
        const float q2 = s_q[c * 4 + 2], q3 = s_q[c * 4 + 3];
        const fvec4* __restrict__ K4 = (const fvec4*)K;
        for (int it = 0; it < START / 16; ++it) {       // 255 exact iterations
            const int s = it * 16 + sr;
            const fvec4 kv = __builtin_nontemporal_load(&K4[s * 16 + c]);
            if (USE_WS) {
                __half2* dst = (__half2*)(Kh + (size_t)s * DIM + c * 4);
                dst[0] = __floats2half2_rn(kv.x, kv.y);
                dst[1] = __floats2half2_rn(kv.z, kv.w);
            }
            float p = kv.x * q0 + kv.y * q1 + kv.z * q2 + kv.w * q3;
            p += __shfl_xor(p, 1);
            p += __shfl_xor(p, 2);
            p += __shfl_xor(p, 4);
            p += __shfl_xor(p, 8);
            if (c == 0) s_scores[s] = p;
        }
        {   // ext rows 4080..4095 from LDS
            const int s = START + sr;
            const float* kr = s_kext[sr];
            float p = kr[c * 4 + 0] * q0 + kr[c * 4 + 1] * q1
                    + kr[c * 4 + 2] * q2 + kr[c * 4 + 3] * q3;
            p += __shfl_xor(p, 1);
            p += __shfl_xor(p, 2);
            p += __shfl_xor(p, 4);
            p += __shfl_xor(p, 8);
            if (c == 0) s_scores[s] = p;
        }
    };

    // ---- QK pass, fp16 shadow cache (steps 1..15) ----
    auto qk_h = [&]() {
        float qv[8];
        #pragma unroll
        for (int j = 0; j < 8; ++j) qv[j] = s_q[c8 * 8 + j];
        const fvec4* __restrict__ Kh4 = (const fvec4*)Kh;
        auto row = [&](int s) {
            fvec4 raw = Kh4[(size_t)s * 8 + c8];
            const __half2* hp = (const __half2*)&raw;
            float p = 0.f;
            #pragma unroll
            for (int j = 0; j < 4; ++j) {
                const float2 f = __half22float2(hp[j]);
                p += f.x * qv[2 * j] + f.y * qv[2 * j + 1];
            }
            p += __shfl_xor(p, 1);
            p += __shfl_xor(p, 2);
            p += __shfl_xor(p, 4);
            if (c8 == 0) s_scores[s] = p;
        };
        for (int it = 0; it < 127; ++it)                  // rows 0..4063
            row(it * 32 + rg);
        if (rg < 16) {                                    // tail 4064..4079
            row(4064 + rg);
            // ext rows 4080..4095 from LDS
            const float* kr = s_kext[rg];
            float p = 0.f;
            #pragma unroll
            for (int j = 0; j < 8; ++j) p += kr[c8 * 8 + j] * qv[j];
            p += __shfl_xor(p, 1);
            p += __shfl_xor(p, 2);
            p += __shfl_xor(p, 4);
            if (c8 == 0) s_scores[START + rg] = p;
        }
    };

    // ---- PV pass, f32 cache (step 0); also emits the fp16 shadow copy ----
    auto pv_f32 = [&](float inv_total) {
        float ax = 0.f, ay = 0.f, az = 0.f, aw = 0.f;
        const fvec4* __restrict__ V4 = (const fvec4*)V;
        for (int it = 0; it < START / 16; ++it) {
            const int s = it * 16 + sr;
            const fvec4 vv = __builtin_nontemporal_load(&V4[s * 16 + c]);
            if (USE_WS) {
                __half2* dst = (__half2*)(Vh + (size_t)s * DIM + c * 4);
                dst[0] = __floats2half2_rn(vv.x, vv.y);
                dst[1] = __floats2half2_rn(vv.z, vv.w);
            }
            const float a = s_scores[s];
            ax += a * vv.x; ay += a * vv.y; az += a * vv.z; aw += a * vv.w;
        }
        {   // ext rows
            const int s = START + sr;
            const float a  = s_scores[s];
            const float* vr = s_vext[sr];
            ax += a * vr[c * 4 + 0]; ay += a * vr[c * 4 + 1];
            az += a * vr[c * 4 + 2]; aw += a * vr[c * 4 + 3];
        }
        ax += __shfl_xor(ax, 16); ax += __shfl_xor(ax, 32);
        ay += __shfl_xor(ay, 16); ay += __shfl_xor(ay, 32);
        az += __shfl_xor(az, 16); az += __shfl_xor(az, 32);
        aw += __shfl_xor(aw, 16); aw += __shfl_xor(aw, 32);
        if ((tid & 63) < 16) {
            s_red[wave][c * 4 + 0] = ax;
            s_red[wave][c * 4 + 1] = ay;
            s_red[wave][c * 4 + 2] = az;
            s_red[wave][c * 4 + 3] = aw;
        }
        __syncthreads();
        if (tid < 64)
            s_attn[tid] = (s_red[0][tid] + s_red[1][tid]
                         + s_red[2][tid] + s_red[3][tid]) * inv_total;
        __syncthreads();
    };

    // ---- PV pass, fp16 shadow cache (steps 1..15) ----
    auto pv_h = [&](float inv_total) {
        float a[8];
        #pragma unroll
        for (int j = 0; j < 8; ++j) a[j] = 0.f;
        const fvec4* __restrict__ Vh4 = (const fvec4*)Vh;
        auto row = [&](int s) {
            const float w = s_scores[s];
            fvec4 raw = Vh4[(size_t)s * 8 + c8];
            const __half2* hp = (const __half2*)&raw;
            #pragma unroll
            for (int j = 0; j < 4; ++j) {
                const float2 f = __half22float2(hp[j]);
                a[2 * j + 0] += w * f.x;
                a[2 * j + 1] += w * f.y;
            }
        };
        for (int it = 0; it < 127; ++it)                  // rows 0..4063
            row(it * 32 + rg);
        if (rg < 16) {                                    // tail 4064..4079
            row(4064 + rg);
            // ext rows from LDS
            const float w = s_scores[START + rg];
            const float* vr = s_vext[rg];
            #pragma unroll
            for (int j = 0; j < 8; ++j) a[j] += w * vr[c8 * 8 + j];
        }
        #pragma unroll
        for (int j = 0; j < 8; ++j) {
            a[j] += __shfl_xor(a[j], 8);
            a[j] += __shfl_xor(a[j], 16);
            a[j] += __shfl_xor(a[j], 32);
        }
        if ((tid & 63) < 8) {
            #pragma unroll
            for (int j = 0; j < 8; ++j) s_red[wave][c8 * 8 + j] = a[j];
        }
        __syncthreads();
        if (tid < 64)
            s_attn[tid] = (s_red[0][tid] + s_red[1][tid]
                         + s_red[2][tid] + s_red[3][tid]) * inv_total;
        __syncthreads();
    };

    for (int step = 0; step < NSTEPS; ++step) {
        // ---- projections (q scaled; k_new/v_new overwrite ext row `step`) ----
        project(s_x, Wq, s_q);
        project(s_x, Wk, s_kext[step]);
        project(s_x, Wv, s_vext[step]);
        if (tid < 64) s_q[tid] *= SCALE;
        __syncthreads();

        if (USE_WS && step > 0) qk_h(); else qk_f32();
        __syncthreads();

        // ---- softmax over 4096 scores (normalization folded into PV) ----
        float lmax = -1e30f;
        #pragma unroll
        for (int i = 0; i < 16; ++i)
            lmax = fmaxf(lmax, s_scores[tid + i * 256]);
        #pragma unroll
        for (int off = 1; off < 64; off <<= 1)
            lmax = fmaxf(lmax, __shfl_xor(lmax, off));
        if ((tid & 63) == 0) s_wred[wave] = lmax;
        __syncthreads();
        const float bmax = fmaxf(fmaxf(s_wred[0], s_wred[1]),
                                 fmaxf(s_wred[2], s_wred[3]));
        float lsum = 0.f;
        #pragma unroll
        for (int i = 0; i < 16; ++i) {
            const float e = __expf(s_scores[tid + i * 256] - bmax);
            s_scores[tid + i * 256] = e;
            lsum += e;
        }
        #pragma unroll
        for (int off = 1; off < 64; off <<= 1)
            lsum += __shfl_xor(lsum, off);
        __syncthreads();                       // s_wred reuse + exp writes
        if ((tid & 63) == 0) s_wred[wave] = lsum;
        __syncthreads();
        const float inv_total = 1.f / (s_wred[0] + s_wred[1]
                                     + s_wred[2] + s_wred[3]);

        if (USE_WS && step > 0) pv_h(inv_total); else pv_f32(inv_total);

        // ---- output projection -> new x ----
        project(s_attn, Wo, s_x);
    }

    if (tid < 64) out[(size_t)bid * DIM + tid] = s_x[tid];
}

extern "C" void kernel_launch(void* const* d_in, const int* in_sizes, int n_in,
                              void* d_out, int out_size, void* d_ws, size_t ws_size,
                              hipStream_t stream) {
    const float* x  = (const float*)d_in[0];
    const float* k  = (const float*)d_in[1];
    const float* v  = (const float*)d_in[2];
    const float* wq = (const float*)d_in[3];
    const float* wk = (const float*)d_in[4];
    const float* wv = (const float*)d_in[5];
    const float* wo = (const float*)d_in[6];
    float* out = (float*)d_out;

    const size_t half_elems = (size_t)BATCH * NHEAD * START * DIM;  // per array
    const size_t need = 2 * half_elems * sizeof(__half);            // K + V

    if (ws_size >= need) {
        __half* kh = (__half*)d_ws;
        __half* vh = kh + half_elems;
        attn_unroll_kernel<true><<<BATCH * NHEAD, 256, 0, stream>>>(
            x, k, v, wq, wk, wv, wo, out, kh, vh);
    } else {
        attn_unroll_kernel<false><<<BATCH * NHEAD, 256, 0, stream>>>(
            x, k, v, wq, wk, wv, wo, out, nullptr, nullptr);
    }
}

// Round 6
// 3329.424 us; speedup vs baseline: 1.2263x; 1.1250x over previous
//
#include <hip/hip_runtime.h>
#include <hip/hip_fp16.h>
#include <math.h>

// Problem geometry (fixed by the reference)
#define BATCH   32
#define NHEAD   32
#define DIM     64
#define SEQ     4096
#define START   4080
#define NSTEPS  16
#define SCALE   0.125f

typedef float fvec4 __attribute__((ext_vector_type(4)));

// One block per (b,h) chain: 1024 blocks x 256 threads (grid-capped at
// 4 blocks/CU), 16 sequential decode steps. fp16 shadow of K/V written
// during step 0, read steps 1..15 (byte floor: 21.4 GB logical).
// Fused flash-decode pass per step: QK^T + online softmax + PV in ONE
// streaming loop (per-wave running max/sum, exact rescale, cross-wave
// merge) -- no s_scores LDS array, no separate softmax phase, K and V
// loads in flight together.
// Row layout: 8 lanes per row (c8 = tid&7), 32 rows per iteration
// (rg = tid>>3). Each lane holds q[8] and acc[8] for dims c8*8..c8*8+7.
template <bool USE_WS>
__launch_bounds__(256, 4)
__global__ void attn_unroll_kernel(const float* __restrict__ x_in,
                                   const float* __restrict__ k_in,
                                   const float* __restrict__ v_in,
                                   const float* __restrict__ wq,
                                   const float* __restrict__ wk,
                                   const float* __restrict__ wv,
                                   const float* __restrict__ wo,
                                   float* __restrict__ out,
                                   __half* __restrict__ kh_ws,
                                   __half* __restrict__ vh_ws)
{
    const int bid = blockIdx.x;          // b*NHEAD + h
    const int h   = bid & (NHEAD - 1);
    const int tid = threadIdx.x;         // 0..255

    __shared__ float s_kext[NSTEPS][DIM];    // 4 KiB (cache tail, f32)
    __shared__ float s_vext[NSTEPS][DIM];    // 4 KiB
    __shared__ float s_x[DIM];
    __shared__ float s_q[DIM];
    __shared__ float s_attn[DIM];
    __shared__ float s_red[4][DIM];          // projection reduce, 1 KiB
    __shared__ float s_wacc[4][DIM];         // per-wave PV accumulators
    __shared__ float s_wm[4], s_wsum[4];     // per-wave online max / sum

    const float* __restrict__ K  = k_in + (size_t)bid * SEQ * DIM;
    const float* __restrict__ V  = v_in + (size_t)bid * SEQ * DIM;
    const float* __restrict__ Wq = wq + (size_t)h * DIM * DIM;
    const float* __restrict__ Wk = wk + (size_t)h * DIM * DIM;
    const float* __restrict__ Wv = wv + (size_t)h * DIM * DIM;
    const float* __restrict__ Wo = wo + (size_t)h * DIM * DIM;
    __half* __restrict__ Kh = USE_WS ? kh_ws + (size_t)bid * START * DIM : nullptr;
    __half* __restrict__ Vh = USE_WS ? vh_ws + (size_t)bid * START * DIM : nullptr;

    // ---- init: x vector + ext rows (original cache tail rows 4080..4095) ----
    if (tid < DIM) s_x[tid] = x_in[(size_t)bid * DIM + tid];
    for (int i = tid; i < NSTEPS * DIM; i += 256) {
        (&s_kext[0][0])[i] = K[(size_t)START * DIM + i];
        (&s_vext[0][0])[i] = V[(size_t)START * DIM + i];
    }
    __syncthreads();

    // out_vec[e] = sum_d in_vec[d] * W[d*64+e]   (einsum "d,de->e")
    auto project = [&](const float* in_vec, const float* __restrict__ W,
                       float* out_vec) {
        const int e = tid & 63;
        const int g = tid >> 6;
        float p = 0.f;
        #pragma unroll
        for (int dd = 0; dd < 16; ++dd) {
            const int d0 = g * 16 + dd;
            p += in_vec[d0] * W[d0 * 64 + e];   // coalesced over e
        }
        s_red[g][e] = p;
        __syncthreads();
        if (tid < 64)
            out_vec[tid] = s_red[0][tid] + s_red[1][tid]
                         + s_red[2][tid] + s_red[3][tid];
        __syncthreads();
    };

    const int c8   = tid & 7;    // 8 lanes per row; lane owns dims c8*8..+7
    const int rg   = tid >> 3;   // row within a 32-row tile [0,32)
    const int wave = tid >> 6;   // [0,4)

    // Online-softmax state (per lane; wave-coherent max)
    float qv[8], acc[8], lsum, om;

    // One row's online update given its score partial p (pre-reduced over
    // dims owned by other lanes of the group) and the 8 V values.
    auto online_row = [&](float p, const float* vv) {
        // score for this group's row -> all 8 lanes of the group
        p += __shfl_xor(p, 1);
        p += __shfl_xor(p, 2);
        p += __shfl_xor(p, 4);
        // wave tile max over the (up to) 8 groups
        float tmax = p;
        tmax = fmaxf(tmax, __shfl_xor(tmax, 8));
        tmax = fmaxf(tmax, __shfl_xor(tmax, 16));
        tmax = fmaxf(tmax, __shfl_xor(tmax, 32));
        const float mn = fmaxf(om, tmax);
        const float f  = __expf(om - mn);          // ==1 when no new max
        om = mn;
        lsum *= f;
        #pragma unroll
        for (int j = 0; j < 8; ++j) acc[j] *= f;
        const float e = __expf(p - om);
        lsum += e;
        #pragma unroll
        for (int j = 0; j < 8; ++j) acc[j] += e * vv[j];
    };

    // finalize: reduce per-wave state, merge across waves -> s_attn
    auto merge = [&]() {
        #pragma unroll
        for (int j = 0; j < 8; ++j) {
            acc[j] += __shfl_xor(acc[j], 8);
            acc[j] += __shfl_xor(acc[j], 16);
            acc[j] += __shfl_xor(acc[j], 32);
        }
        lsum += __shfl_xor(lsum, 8);
        lsum += __shfl_xor(lsum, 16);
        lsum += __shfl_xor(lsum, 32);
        if ((tid & 63) == 0) { s_wm[wave] = om; s_wsum[wave] = lsum; }
        if ((tid & 63) < 8) {
            #pragma unroll
            for (int j = 0; j < 8; ++j) s_wacc[wave][c8 * 8 + j] = acc[j];
        }
        __syncthreads();
        if (tid < 64) {
            const float M = fmaxf(fmaxf(s_wm[0], s_wm[1]),
                                  fmaxf(s_wm[2], s_wm[3]));
            float tot = 0.f, val = 0.f;
            #pragma unroll
            for (int w = 0; w < 4; ++w) {
                const float f = __expf(s_wm[w] - M);
                tot += s_wsum[w] * f;
                val += s_wacc[w][tid] * f;
            }
            s_attn[tid] = val / tot;
        }
        __syncthreads();
    };

    // ext rows 4080..4095 from LDS (waves 0,1; rg in [0,16))
    auto ext_rows = [&]() {
        if (wave < 2) {
            const float* kr = s_kext[rg];
            const float* vr = s_vext[rg];
            float p = 0.f;
            #pragma unroll
            for (int j = 0; j < 8; ++j) p += kr[c8 * 8 + j] * qv[j];
            float vv[8];
            #pragma unroll
            for (int j = 0; j < 8; ++j) vv[j] = vr[c8 * 8 + j];
            online_row(p, vv);
        }
    };

    // ---- fused pass, f32 cache (step 0); emits the fp16 shadow copy ----
    auto pass_f32 = [&]() {
        #pragma unroll
        for (int j = 0; j < 8; ++j) qv[j] = s_q[c8 * 8 + j];
        #pragma unroll
        for (int j = 0; j < 8; ++j) acc[j] = 0.f;
        lsum = 0.f; om = -1e30f;
        const fvec4* __restrict__ K4 = (const fvec4*)K;
        const fvec4* __restrict__ V4 = (const fvec4*)V;
        auto row = [&](int s) {
            const fvec4 ka = K4[(size_t)s * 16 + 2 * c8];
            const fvec4 kb = K4[(size_t)s * 16 + 2 * c8 + 1];
            const fvec4 va = V4[(size_t)s * 16 + 2 * c8];
            const fvec4 vb = V4[(size_t)s * 16 + 2 * c8 + 1];
            if (USE_WS) {
                union { fvec4 v; __half2 hh[4]; } uk, uv;
                uk.hh[0] = __floats2half2_rn(ka.x, ka.y);
                uk.hh[1] = __floats2half2_rn(ka.z, ka.w);
                uk.hh[2] = __floats2half2_rn(kb.x, kb.y);
                uk.hh[3] = __floats2half2_rn(kb.z, kb.w);
                uv.hh[0] = __floats2half2_rn(va.x, va.y);
                uv.hh[1] = __floats2half2_rn(va.z, va.w);
                uv.hh[2] = __floats2half2_rn(vb.x, vb.y);
                uv.hh[3] = __floats2half2_rn(vb.z, vb.w);
                *(fvec4*)(Kh + (size_t)s * DIM + c8 * 8) = uk.v;
                *(fvec4*)(Vh + (size_t)s * DIM + c8 * 8) = uv.v;
            }
            float p = ka.x * qv[0] + ka.y * qv[1] + ka.z * qv[2] + ka.w * qv[3]
                    + kb.x * qv[4] + kb.y * qv[5] + kb.z * qv[6] + kb.w * qv[7];
            const float vv[8] = { va.x, va.y, va.z, va.w,
                                  vb.x, vb.y, vb.z, vb.w };
            online_row(p, vv);
        };
        for (int it = 0; it < 127; ++it)       // rows 0..4063
            row(it * 32 + rg);
        if (wave < 2)                          // tail rows 4064..4079
            row(4064 + rg);
        ext_rows();
        merge();
    };

    // ---- fused pass, fp16 shadow cache (steps 1..15) ----
    auto pass_h = [&]() {
        #pragma unroll
        for (int j = 0; j < 8; ++j) qv[j] = s_q[c8 * 8 + j];
        #pragma unroll
        for (int j = 0; j < 8; ++j) acc[j] = 0.f;
        lsum = 0.f; om = -1e30f;
        const fvec4* __restrict__ Kh4 = (const fvec4*)Kh;
        const fvec4* __restrict__ Vh4 = (const fvec4*)Vh;
        auto row = [&](int s) {
            fvec4 kraw = Kh4[(size_t)s * 8 + c8];
            fvec4 vraw = Vh4[(size_t)s * 8 + c8];
            const __half2* kp = (const __half2*)&kraw;
            const __half2* vp = (const __half2*)&vraw;
            float p = 0.f;
            #pragma unroll
            for (int j = 0; j < 4; ++j) {
                const float2 f = __half22float2(kp[j]);
                p += f.x * qv[2 * j] + f.y * qv[2 * j + 1];
            }
            float vv[8];
            #pragma unroll
            for (int j = 0; j < 4; ++j) {
                const float2 f = __half22float2(vp[j]);
                vv[2 * j + 0] = f.x;
                vv[2 * j + 1] = f.y;
            }
            online_row(p, vv);
        };
        for (int it = 0; it < 127; ++it)       // rows 0..4063
            row(it * 32 + rg);
        if (wave < 2)                          // tail rows 4064..4079
            row(4064 + rg);
        ext_rows();
        merge();
    };

    for (int step = 0; step < NSTEPS; ++step) {
        // ---- projections (q scaled; k_new/v_new overwrite ext row `step`) ----
        project(s_x, Wq, s_q);
        project(s_x, Wk, s_kext[step]);
        project(s_x, Wv, s_vext[step]);
        if (tid < 64) s_q[tid] *= SCALE;
        __syncthreads();

        if (USE_WS && step > 0) pass_h(); else pass_f32();

        // ---- output projection -> new x ----
        project(s_attn, Wo, s_x);
    }

    if (tid < 64) out[(size_t)bid * DIM + tid] = s_x[tid];
}

extern "C" void kernel_launch(void* const* d_in, const int* in_sizes, int n_in,
                              void* d_out, int out_size, void* d_ws, size_t ws_size,
                              hipStream_t stream) {
    const float* x  = (const float*)d_in[0];
    const float* k  = (const float*)d_in[1];
    const float* v  = (const float*)d_in[2];
    const float* wq = (const float*)d_in[3];
    const float* wk = (const float*)d_in[4];
    const float* wv = (const float*)d_in[5];
    const float* wo = (const float*)d_in[6];
    float* out = (float*)d_out;

    const size_t half_elems = (size_t)BATCH * NHEAD * START * DIM;  // per array
    const size_t need = 2 * half_elems * sizeof(__half);            // K + V

    if (ws_size >= need) {
        __half* kh = (__half*)d_ws;
        __half* vh = kh + half_elems;
        attn_unroll_kernel<true><<<BATCH * NHEAD, 256, 0, stream>>>(
            x, k, v, wq, wk, wv, wo, out, kh, vh);
    } else {
        attn_unroll_kernel<false><<<BATCH * NHEAD, 256, 0, stream>>>(
            x, k, v, wq, wk, wv, wo, out, nullptr, nullptr);
    }
}